// Round 1
// baseline (134.944 us; speedup 1.0000x reference)
//
#include <hip/hip_runtime.h>
#include <hip/hip_bf16.h>
#include <stdint.h>

#define T_SEQ 4096
#define CDIM  1024
#define NH    16
#define NKV   4
#define HD    64
#define WIN   512
#define KVD   256      // NKV*HD
#define QKVN  1536     // CDIM + 2*KVD

typedef unsigned short ushort_t;
typedef __attribute__((ext_vector_type(8))) __bf16 bf16x8;
typedef __attribute__((ext_vector_type(4))) float  f32x4;
typedef __attribute__((ext_vector_type(4))) unsigned short us4;

__device__ inline unsigned short f2bf(float f) {
  unsigned u = __builtin_bit_cast(unsigned, f);
  u += 0x7fffu + ((u >> 16) & 1u);
  return (unsigned short)(u >> 16);
}

__device__ inline f32x4 mfma16(bf16x8 a, bf16x8 b, f32x4 c) {
  return __builtin_amdgcn_mfma_f32_16x16x32_bf16(a, b, c, 0, 0, 0);
}

__device__ inline void load_lds16(const void* g, void* s) {
  __builtin_amdgcn_global_load_lds(
      (const __attribute__((address_space(1))) void*)g,
      (__attribute__((address_space(3))) void*)s, 16, 0, 0);
}

// ---------------- prep: f32 -> bf16 conversions ----------------
__global__ __launch_bounds__(256) void prep_kernel(
    const float* __restrict__ x,  const float* __restrict__ wq,
    const float* __restrict__ wk, const float* __restrict__ wv,
    const float* __restrict__ wo,
    ushort_t* __restrict__ xb, ushort_t* __restrict__ wqkvb,
    ushort_t* __restrict__ wob) {
  const int NX  = T_SEQ * CDIM / 4;   // 1048576 vec4s
  const int NWQ = CDIM * CDIM / 4;    // 262144
  const int NWK = KVD * CDIM / 4;     // 65536
  int i = blockIdx.x * 256 + threadIdx.x;
  const float4* src; ushort_t* dst; int off;
  if (i < NX)                        { src = (const float4*)x;  dst = xb;                              off = i; }
  else if (i < NX + NWQ)             { src = (const float4*)wq; dst = wqkvb;                           off = i - NX; }
  else if (i < NX + NWQ + NWK)       { src = (const float4*)wk; dst = wqkvb + CDIM * CDIM;             off = i - NX - NWQ; }
  else if (i < NX + NWQ + 2 * NWK)   { src = (const float4*)wv; dst = wqkvb + CDIM * CDIM + KVD * CDIM; off = i - NX - NWQ - NWK; }
  else if (i < NX + 2 * NWQ + 2 * NWK){ src = (const float4*)wo; dst = wob;                            off = i - NX - NWQ - 2 * NWK; }
  else return;
  float4 v = src[off];
  us4 o; o.x = f2bf(v.x); o.y = f2bf(v.y); o.z = f2bf(v.z); o.w = f2bf(v.w);
  *(us4*)(dst + (size_t)off * 4) = o;
}

// ---------------- rope tables ----------------
__global__ __launch_bounds__(256) void rope_kernel(float* __restrict__ ct, float* __restrict__ st) {
  int i = blockIdx.x * 256 + threadIdx.x;   // T*32
  if (i >= T_SEQ * 32) return;
  int t = i >> 5, f = i & 31;
  // inv_freq = 10000^(-f/32) = 2^(-f/32 * log2(10000))
  float inv = __builtin_exp2f(-(float)f * (13.287712379549449f / 32.0f));
  float a = (float)t * inv;
  ct[i] = cosf(a);
  st[i] = sinf(a);
}

// ---------------- GEMM: C = A(MxK) * B(NxK)^T, bf16 in, f32 acc ----------------
// EPI 0: QKV epilogue (rope Q/K, V transposed to [kvh*64+d][T])
// EPI 1: f32 store to outF [M][1024]
template <int EPI>
__global__ __launch_bounds__(256) void gemm_kernel(
    const ushort_t* __restrict__ A, const ushort_t* __restrict__ B, int K,
    float* __restrict__ outF,
    ushort_t* __restrict__ qbuf, ushort_t* __restrict__ kbuf, ushort_t* __restrict__ vt,
    const float* __restrict__ ct, const float* __restrict__ st) {
  __shared__ __align__(16) ushort_t smA[128 * 32];
  __shared__ __align__(16) ushort_t smB[128 * 32];
  const int tid = threadIdx.x, lane = tid & 63, wid = tid >> 6;
  const int bm = blockIdx.x * 128, bn = blockIdx.y * 128;
  const int wr = wid >> 1, wc = wid & 1;
  const int l15 = lane & 15, lg = lane >> 4;
  const int srow = lane >> 2;        // 0..15
  const int scol = (lane & 3) * 8;   // 0,8,16,24

  f32x4 acc[4][4];
#pragma unroll
  for (int i = 0; i < 4; i++)
#pragma unroll
    for (int j = 0; j < 4; j++) acc[i][j] = (f32x4)0.0f;

  for (int kt = 0; kt < K; kt += 32) {
#pragma unroll
    for (int i = 0; i < 2; i++) {
      int ch = i * 4 + wid;  // 0..7, per-wave uniform
      load_lds16(A + (size_t)(bm + ch * 16 + srow) * K + kt + scol, (char*)smA + ch * 1024);
      load_lds16(B + (size_t)(bn + ch * 16 + srow) * K + kt + scol, (char*)smB + ch * 1024);
    }
    __syncthreads();
    bf16x8 af[4], bfr[4];
#pragma unroll
    for (int mi = 0; mi < 4; mi++) af[mi] = *(const bf16x8*)&smA[(wr * 64 + mi * 16 + l15) * 32 + lg * 8];
#pragma unroll
    for (int ni = 0; ni < 4; ni++) bfr[ni] = *(const bf16x8*)&smB[(wc * 64 + ni * 16 + l15) * 32 + lg * 8];
#pragma unroll
    for (int mi = 0; mi < 4; mi++)
#pragma unroll
      for (int ni = 0; ni < 4; ni++) acc[mi][ni] = mfma16(af[mi], bfr[ni], acc[mi][ni]);
    __syncthreads();
  }

  const int col0 = bn + wc * 64;  // wave's 64-col span, multiple of 64
  if (EPI == 1) {
#pragma unroll
    for (int mi = 0; mi < 4; mi++) {
      int r0 = bm + wr * 64 + mi * 16 + lg * 4;
#pragma unroll
      for (int ni = 0; ni < 4; ni++) {
        int c = col0 + ni * 16 + l15;
#pragma unroll
        for (int r = 0; r < 4; r++) outF[(size_t)(r0 + r) * CDIM + c] = acc[mi][ni][r];
      }
    }
  } else {
    if (col0 < CDIM + KVD) {
      // Q or K: apply rope. pairs (d, d+32) are frags ni and ni+2, same lane.
      bool isQ = (col0 < CDIM);
      ushort_t* obuf = isQ ? qbuf : kbuf;
      int ostride = isQ ? CDIM : KVD;
      int obase = isQ ? col0 : col0 - CDIM;
#pragma unroll
      for (int mi = 0; mi < 4; mi++) {
        int r0 = bm + wr * 64 + mi * 16 + lg * 4;
#pragma unroll
        for (int ni = 0; ni < 2; ni++) {
          int dd = ni * 16 + l15;  // 0..31 within head
#pragma unroll
          for (int r = 0; r < 4; r++) {
            int t = r0 + r;
            float c_ = ct[t * 32 + dd], s_ = st[t * 32 + dd];
            float lo = acc[mi][ni][r], hi = acc[mi][ni + 2][r];
            obuf[(size_t)t * ostride + obase + dd]      = f2bf(lo * c_ - hi * s_);
            obuf[(size_t)t * ostride + obase + dd + 32] = f2bf(hi * c_ + lo * s_);
          }
        }
      }
    } else {
      // V: transpose to vt[cv][T], cv = kvh*64+d. 4 consecutive rows -> 8B store.
#pragma unroll
      for (int mi = 0; mi < 4; mi++) {
        int t0 = bm + wr * 64 + mi * 16 + lg * 4;
#pragma unroll
        for (int ni = 0; ni < 4; ni++) {
          int cv = col0 + ni * 16 + l15 - (CDIM + KVD);  // 0..255
          us4 o;
          o.x = f2bf(acc[mi][ni][0]); o.y = f2bf(acc[mi][ni][1]);
          o.z = f2bf(acc[mi][ni][2]); o.w = f2bf(acc[mi][ni][3]);
          *(us4*)&vt[(size_t)cv * T_SEQ + t0] = o;
        }
      }
    }
  }
}

// ---------------- flash attention, sliding window ----------------
// 1 wave per (head, 16-query tile). S^T = mfma(K, Q); P via per-wave LDS; O = mfma(P, V^T).
__global__ __launch_bounds__(256) void attn_kernel(
    const ushort_t* __restrict__ qbuf, const ushort_t* __restrict__ kbuf,
    const ushort_t* __restrict__ vt, ushort_t* __restrict__ ybuf) {
  __shared__ __align__(16) ushort_t plds[4][16 * 40];  // per-wave, stride 40 pads banks
  const int tid = threadIdx.x, lane = tid & 63, wid = tid >> 6;
  const int l15 = lane & 15, lg = lane >> 4;
  int w = blockIdx.x * 4 + wid;
  int h = w >> 8;             // 256 q-tiles per head
  int qb = (w & 255) * 16;
  int kvh = h >> 2;           // n_rep = 4

  const ushort_t* qrow = qbuf + (size_t)(qb + l15) * CDIM + h * HD;
  bf16x8 qf0 = *(const bf16x8*)(qrow + lg * 8);
  bf16x8 qf1 = *(const bf16x8*)(qrow + 32 + lg * 8);

  f32x4 o0 = (f32x4)0.f, o1 = (f32x4)0.f, o2 = (f32x4)0.f, o3 = (f32x4)0.f;
  float m_run = -1e30f, l_run = 0.f;
  const float SC = 0.125f * 1.4426950408889634f;  // scale * log2(e)
  const int q = qb + l15;
  ushort_t* pl = &plds[wid][0];
  const ushort_t* vb_base = vt + (size_t)(kvh * HD) * T_SEQ;

  int kb0 = qb - (WIN - 1);
  if (kb0 < 0) kb0 = 0;
  kb0 &= ~31;

  for (int kb = kb0; kb <= qb + 15; kb += 32) {
    const ushort_t* kr0 = kbuf + (size_t)(kb + l15) * KVD + kvh * HD + lg * 8;
    const ushort_t* kr1 = kr0 + (size_t)16 * KVD;
    f32x4 s0 = (f32x4)0.f, s1 = (f32x4)0.f;
    s0 = mfma16(*(const bf16x8*)kr0, qf0, s0);
    s1 = mfma16(*(const bf16x8*)kr1, qf0, s1);
    s0 = mfma16(*(const bf16x8*)(kr0 + 32), qf1, s0);
    s1 = mfma16(*(const bf16x8*)(kr1 + 32), qf1, s1);

    float sv[8];
    float mx = -3e38f;
#pragma unroll
    for (int r = 0; r < 4; r++) {
      int k0 = kb + lg * 4 + r;
      int k1 = k0 + 16;
      float a = (k0 <= q && k0 > q - WIN) ? s0[r] * SC : -3e38f;
      float b = (k1 <= q && k1 > q - WIN) ? s1[r] * SC : -3e38f;
      sv[r] = a; sv[4 + r] = b;
      mx = fmaxf(mx, fmaxf(a, b));
    }
    mx = fmaxf(mx, __shfl_xor(mx, 16));
    mx = fmaxf(mx, __shfl_xor(mx, 32));
    float m_new = fmaxf(m_run, mx);
    float fac = __builtin_exp2f(m_run - m_new);
    float psum = 0.f;
    unsigned short pb[8];
#pragma unroll
    for (int j = 0; j < 8; j++) {
      float p = __builtin_exp2f(sv[j] - m_new);
      psum += p;
      pb[j] = f2bf(p);
    }
    psum += __shfl_xor(psum, 16);
    psum += __shfl_xor(psum, 32);
    l_run = l_run * fac + psum;
    m_run = m_new;

    // P^T (reg layout) -> LDS -> P as A-operand
    us4 w0; w0.x = pb[0]; w0.y = pb[1]; w0.z = pb[2]; w0.w = pb[3];
    us4 w1; w1.x = pb[4]; w1.y = pb[5]; w1.z = pb[6]; w1.w = pb[7];
    *(us4*)&pl[l15 * 40 + lg * 4] = w0;
    *(us4*)&pl[l15 * 40 + 16 + lg * 4] = w1;
    asm volatile("s_waitcnt lgkmcnt(0)" ::: "memory");
    __builtin_amdgcn_sched_barrier(0);
    bf16x8 pf = *(const bf16x8*)&pl[l15 * 40 + lg * 8];

    // rescale O rows (q = lg*4+r) by fac (held at lane q)
    float f0 = __shfl(fac, lg * 4 + 0);
    float f1 = __shfl(fac, lg * 4 + 1);
    float f2 = __shfl(fac, lg * 4 + 2);
    float f3 = __shfl(fac, lg * 4 + 3);
    o0[0] *= f0; o0[1] *= f1; o0[2] *= f2; o0[3] *= f3;
    o1[0] *= f0; o1[1] *= f1; o1[2] *= f2; o1[3] *= f3;
    o2[0] *= f0; o2[1] *= f1; o2[2] *= f2; o2[3] *= f3;
    o3[0] *= f0; o3[1] *= f1; o3[2] *= f2; o3[3] *= f3;

    const ushort_t* vb = vb_base + kb + lg * 8;
    o0 = mfma16(pf, *(const bf16x8*)(vb + (size_t)(0  + l15) * T_SEQ), o0);
    o1 = mfma16(pf, *(const bf16x8*)(vb + (size_t)(16 + l15) * T_SEQ), o1);
    o2 = mfma16(pf, *(const bf16x8*)(vb + (size_t)(32 + l15) * T_SEQ), o2);
    o3 = mfma16(pf, *(const bf16x8*)(vb + (size_t)(48 + l15) * T_SEQ), o3);
  }

  float inv = 1.f / l_run;
  float i0 = __shfl(inv, lg * 4 + 0);
  float i1 = __shfl(inv, lg * 4 + 1);
  float i2 = __shfl(inv, lg * 4 + 2);
  float i3 = __shfl(inv, lg * 4 + 3);
  ushort_t* yb = ybuf + (size_t)qb * CDIM + h * HD;
#pragma unroll
  for (int r = 0; r < 4; r++) {
    float ir = (r == 0) ? i0 : (r == 1) ? i1 : (r == 2) ? i2 : i3;
    size_t t = lg * 4 + r;
    yb[t * CDIM + 0  + l15] = f2bf(o0[r] * ir);
    yb[t * CDIM + 16 + l15] = f2bf(o1[r] * ir);
    yb[t * CDIM + 32 + l15] = f2bf(o2[r] * ir);
    yb[t * CDIM + 48 + l15] = f2bf(o3[r] * ir);
  }
}

// ---------------- launch ----------------
extern "C" void kernel_launch(void* const* d_in, const int* in_sizes, int n_in,
                              void* d_out, int out_size, void* d_ws, size_t ws_size,
                              hipStream_t stream) {
  const float* x  = (const float*)d_in[0];
  const float* wq = (const float*)d_in[1];
  const float* wk = (const float*)d_in[2];
  const float* wv = (const float*)d_in[3];
  const float* wo = (const float*)d_in[4];
  float* out = (float*)d_out;

  char* ws = (char*)d_ws;
  // layout (bytes):
  ushort_t* xb    = (ushort_t*)(ws + 0);          // 8,388,608
  ushort_t* wqkvb = (ushort_t*)(ws + 8388608);    // 3,145,728
  ushort_t* wob   = (ushort_t*)(ws + 11534336);   // 2,097,152
  ushort_t* qbuf  = (ushort_t*)(ws + 13631488);   // 8,388,608
  ushort_t* kbuf  = (ushort_t*)(ws + 22020096);   // 2,097,152 (vt follows: absorbs tail over-read)
  ushort_t* vt    = (ushort_t*)(ws + 24117248);   // 2,097,152 (ybuf follows: absorbs tail over-read)
  ushort_t* ybuf  = (ushort_t*)(ws + 26214400);   // 8,388,608
  float*    ct    = (float*)(ws + 34603008);      // 524,288
  float*    st    = (float*)(ws + 35127296);      // 524,288  -> total ~35.7 MB

  prep_kernel<<<6656, 256, 0, stream>>>(x, wq, wk, wv, wo, xb, wqkvb, wob);
  rope_kernel<<<512, 256, 0, stream>>>(ct, st);

  dim3 g1(32, 12);  // M/128 x QKVN/128
  gemm_kernel<0><<<g1, 256, 0, stream>>>(xb, wqkvb, CDIM, nullptr, qbuf, kbuf, vt, ct, st);

  attn_kernel<<<1024, 256, 0, stream>>>(qbuf, kbuf, vt, ybuf);

  dim3 g2(32, 8);   // M/128 x CDIM/128
  gemm_kernel<1><<<g2, 256, 0, stream>>>(ybuf, wob, CDIM, out, nullptr, nullptr, nullptr, nullptr, nullptr);
}

// Round 2
// 101.145 us; speedup vs baseline: 1.3342x; 1.3342x over previous
//
#include <hip/hip_runtime.h>
#include <hip/hip_bf16.h>
#include <stdint.h>

#define T_SEQ 4096
#define CDIM  1024
#define NH    16
#define NKV   4
#define HD    64
#define WIN   512
#define KVD   256      // NKV*HD
#define QKVN  1536     // CDIM + 2*KVD

typedef unsigned short ushort_t;
typedef __attribute__((ext_vector_type(8))) __bf16 bf16x8;
typedef __attribute__((ext_vector_type(4))) float  f32x4;
typedef __attribute__((ext_vector_type(4))) unsigned short us4;

__device__ inline unsigned short f2bf(float f) {
  unsigned u = __builtin_bit_cast(unsigned, f);
  u += 0x7fffu + ((u >> 16) & 1u);
  return (unsigned short)(u >> 16);
}

__device__ inline f32x4 mfma16(bf16x8 a, bf16x8 b, f32x4 c) {
  return __builtin_amdgcn_mfma_f32_16x16x32_bf16(a, b, c, 0, 0, 0);
}

__device__ inline void load_lds16(const void* g, void* s) {
  __builtin_amdgcn_global_load_lds(
      (const __attribute__((address_space(1))) void*)g,
      (__attribute__((address_space(3))) void*)s, 16, 0, 0);
}

// ---------------- prep: f32 -> bf16 conversions ----------------
__global__ __launch_bounds__(256) void prep_kernel(
    const float* __restrict__ x,  const float* __restrict__ wq,
    const float* __restrict__ wk, const float* __restrict__ wv,
    const float* __restrict__ wo,
    ushort_t* __restrict__ xb, ushort_t* __restrict__ wqkvb,
    ushort_t* __restrict__ wob) {
  const int NX  = T_SEQ * CDIM / 4;   // 1048576 vec4s
  const int NWQ = CDIM * CDIM / 4;    // 262144
  const int NWK = KVD * CDIM / 4;     // 65536
  int i = blockIdx.x * 256 + threadIdx.x;
  const float4* src; ushort_t* dst; int off;
  if (i < NX)                        { src = (const float4*)x;  dst = xb;                              off = i; }
  else if (i < NX + NWQ)             { src = (const float4*)wq; dst = wqkvb;                           off = i - NX; }
  else if (i < NX + NWQ + NWK)       { src = (const float4*)wk; dst = wqkvb + CDIM * CDIM;             off = i - NX - NWQ; }
  else if (i < NX + NWQ + 2 * NWK)   { src = (const float4*)wv; dst = wqkvb + CDIM * CDIM + KVD * CDIM; off = i - NX - NWQ - NWK; }
  else if (i < NX + 2 * NWQ + 2 * NWK){ src = (const float4*)wo; dst = wob;                            off = i - NX - NWQ - 2 * NWK; }
  else return;
  float4 v = src[off];
  us4 o; o.x = f2bf(v.x); o.y = f2bf(v.y); o.z = f2bf(v.z); o.w = f2bf(v.w);
  *(us4*)(dst + (size_t)off * 4) = o;
}

// ---------------- rope tables ----------------
__global__ __launch_bounds__(256) void rope_kernel(float* __restrict__ ct, float* __restrict__ st) {
  int i = blockIdx.x * 256 + threadIdx.x;   // T*32
  if (i >= T_SEQ * 32) return;
  int t = i >> 5, f = i & 31;
  float inv = __builtin_exp2f(-(float)f * (13.287712379549449f / 32.0f));
  float a = (float)t * inv;
  ct[i] = cosf(a);
  st[i] = sinf(a);
}

// ---------------- GEMM: C = A(MxK) * B(NxK)^T, bf16 in, f32 acc ----------------
template <int EPI>
__global__ __launch_bounds__(256) void gemm_kernel(
    const ushort_t* __restrict__ A, const ushort_t* __restrict__ B, int K,
    float* __restrict__ outF,
    ushort_t* __restrict__ qbuf, ushort_t* __restrict__ kbuf, ushort_t* __restrict__ vt,
    const float* __restrict__ ct, const float* __restrict__ st) {
  __shared__ __align__(16) ushort_t smA[128 * 32];
  __shared__ __align__(16) ushort_t smB[128 * 32];
  const int tid = threadIdx.x, lane = tid & 63, wid = tid >> 6;
  const int bm = blockIdx.x * 128, bn = blockIdx.y * 128;
  const int wr = wid >> 1, wc = wid & 1;
  const int l15 = lane & 15, lg = lane >> 4;
  const int srow = lane >> 2;        // 0..15
  const int scol = (lane & 3) * 8;   // 0,8,16,24

  f32x4 acc[4][4];
#pragma unroll
  for (int i = 0; i < 4; i++)
#pragma unroll
    for (int j = 0; j < 4; j++) acc[i][j] = (f32x4)0.0f;

  for (int kt = 0; kt < K; kt += 32) {
#pragma unroll
    for (int i = 0; i < 2; i++) {
      int ch = i * 4 + wid;  // 0..7, per-wave uniform
      load_lds16(A + (size_t)(bm + ch * 16 + srow) * K + kt + scol, (char*)smA + ch * 1024);
      load_lds16(B + (size_t)(bn + ch * 16 + srow) * K + kt + scol, (char*)smB + ch * 1024);
    }
    __syncthreads();
    bf16x8 af[4], bfr[4];
#pragma unroll
    for (int mi = 0; mi < 4; mi++) af[mi] = *(const bf16x8*)&smA[(wr * 64 + mi * 16 + l15) * 32 + lg * 8];
#pragma unroll
    for (int ni = 0; ni < 4; ni++) bfr[ni] = *(const bf16x8*)&smB[(wc * 64 + ni * 16 + l15) * 32 + lg * 8];
#pragma unroll
    for (int mi = 0; mi < 4; mi++)
#pragma unroll
      for (int ni = 0; ni < 4; ni++) acc[mi][ni] = mfma16(af[mi], bfr[ni], acc[mi][ni]);
    __syncthreads();
  }

  const int col0 = bn + wc * 64;  // wave's 64-col span, multiple of 64
  if (EPI == 1) {
#pragma unroll
    for (int mi = 0; mi < 4; mi++) {
      int r0 = bm + wr * 64 + mi * 16 + lg * 4;
#pragma unroll
      for (int ni = 0; ni < 4; ni++) {
        int c = col0 + ni * 16 + l15;
#pragma unroll
        for (int r = 0; r < 4; r++) outF[(size_t)(r0 + r) * CDIM + c] = acc[mi][ni][r];
      }
    }
  } else {
    if (col0 < CDIM + KVD) {
      // Q or K: apply rope. pairs (d, d+32) are frags ni and ni+2, same lane.
      bool isQ = (col0 < CDIM);
      ushort_t* obuf = isQ ? qbuf : kbuf;
      int ostride = isQ ? CDIM : KVD;
      int obase = isQ ? col0 : col0 - CDIM;
#pragma unroll
      for (int mi = 0; mi < 4; mi++) {
        int r0 = bm + wr * 64 + mi * 16 + lg * 4;
#pragma unroll
        for (int ni = 0; ni < 2; ni++) {
          int dd = ni * 16 + l15;  // 0..31 within head
#pragma unroll
          for (int r = 0; r < 4; r++) {
            int t = r0 + r;
            float c_ = ct[t * 32 + dd], s_ = st[t * 32 + dd];
            float lo = acc[mi][ni][r], hi = acc[mi][ni + 2][r];
            obuf[(size_t)t * ostride + obase + dd]      = f2bf(lo * c_ - hi * s_);
            obuf[(size_t)t * ostride + obase + dd + 32] = f2bf(hi * c_ + lo * s_);
          }
        }
      }
    } else {
      // V: transpose to vt[cv][T], cv = kvh*64+d. 4 consecutive rows -> 8B store.
#pragma unroll
      for (int mi = 0; mi < 4; mi++) {
        int t0 = bm + wr * 64 + mi * 16 + lg * 4;
#pragma unroll
        for (int ni = 0; ni < 4; ni++) {
          int cv = col0 + ni * 16 + l15 - (CDIM + KVD);  // 0..255
          us4 o;
          o.x = f2bf(acc[mi][ni][0]); o.y = f2bf(acc[mi][ni][1]);
          o.z = f2bf(acc[mi][ni][2]); o.w = f2bf(acc[mi][ni][3]);
          *(us4*)&vt[(size_t)cv * T_SEQ + t0] = o;
        }
      }
    }
  }
}

// ---------------- flash attention, sliding window ----------------
// Block = 64 queries of one head, 4 waves x 16 queries. KBLK = 64.
// K tile [64 keys][64 d] and V^T tile [64 d][64 keys] staged in LDS via
// global_load_lds (linear dest) with per-row XOR chunk swizzle on the
// global source addresses; ds_read_b128 fragment reads apply the same XOR.
__global__ __launch_bounds__(256) void attn_kernel(
    const ushort_t* __restrict__ qbuf, const ushort_t* __restrict__ kbuf,
    const ushort_t* __restrict__ vt, ushort_t* __restrict__ ybuf) {
  __shared__ __align__(16) ushort_t smK[64 * 64];
  __shared__ __align__(16) ushort_t smV[64 * 64];
  __shared__ __align__(16) ushort_t plds[4][16 * 72];  // per-wave P transpose buffer
  const int tid = threadIdx.x, lane = tid & 63, wid = tid >> 6;
  const int l15 = lane & 15, lg = lane >> 4;
  const int blk = blockIdx.x;
  const int h = blk >> 6;            // 64 q-tiles per head
  const int qb = (blk & 63) * 64;    // block query base
  const int kvh = h >> 2;            // n_rep = 4
  const int qbw = qb + wid * 16;     // wave query base

  // Q fragments (held in registers for whole kernel)
  const ushort_t* qrow = qbuf + (size_t)(qbw + l15) * CDIM + h * HD;
  bf16x8 qf0 = *(const bf16x8*)(qrow + lg * 8);
  bf16x8 qf1 = *(const bf16x8*)(qrow + 32 + lg * 8);

  f32x4 o0 = (f32x4)0.f, o1 = (f32x4)0.f, o2 = (f32x4)0.f, o3 = (f32x4)0.f;
  float m_run = -1e30f, l_run = 0.f;
  const float SC = 0.125f * 1.4426950408889634f;  // scale * log2(e)
  const int q = qbw + l15;
  ushort_t* pl = &plds[wid][0];

  // staging lane decomposition: inst covers 8 rows of 128B; lane -> (row, chunk)
  const int r8 = lane >> 3;          // 0..7 row within inst
  const int cc = lane & 7;           // dest 16B chunk within row
  const int sc = ((cc ^ r8) * 8);    // swizzled source elem offset within row

  int kb0 = qb - (WIN - 1);
  if (kb0 < 0) kb0 = 0;
  kb0 &= ~63;

  for (int kb = kb0; kb <= qb + 63; kb += 64) {
    // ---- cooperative staging: 8 insts each for K and V, 2 per wave ----
    {
      int ra = wid * 8 + r8;         // rows for inst j = wid
      int rb = (wid + 4) * 8 + r8;   // rows for inst j = wid + 4
      load_lds16(kbuf + (size_t)(kb + ra) * KVD + kvh * HD + sc, (char*)smK + wid * 1024);
      load_lds16(kbuf + (size_t)(kb + rb) * KVD + kvh * HD + sc, (char*)smK + (wid + 4) * 1024);
      load_lds16(vt + (size_t)(kvh * HD + ra) * T_SEQ + kb + sc, (char*)smV + wid * 1024);
      load_lds16(vt + (size_t)(kvh * HD + rb) * T_SEQ + kb + sc, (char*)smV + (wid + 4) * 1024);
    }
    __syncthreads();  // compiler drains vmcnt before s_barrier

    // ---- QK^T: S^T[k][q], 4 key groups of 16 ----
    f32x4 s0, s1, s2, s3;
    {
      int krow, sw;
      krow = 0 * 16 + l15; sw = krow & 7;
      s0 = mfma16(*(const bf16x8*)&smK[krow * 64 + ((lg ^ sw) * 8)], qf0, (f32x4)0.f);
      s0 = mfma16(*(const bf16x8*)&smK[krow * 64 + (((4 + lg) ^ sw) * 8)], qf1, s0);
      krow = 1 * 16 + l15; sw = krow & 7;
      s1 = mfma16(*(const bf16x8*)&smK[krow * 64 + ((lg ^ sw) * 8)], qf0, (f32x4)0.f);
      s1 = mfma16(*(const bf16x8*)&smK[krow * 64 + (((4 + lg) ^ sw) * 8)], qf1, s1);
      krow = 2 * 16 + l15; sw = krow & 7;
      s2 = mfma16(*(const bf16x8*)&smK[krow * 64 + ((lg ^ sw) * 8)], qf0, (f32x4)0.f);
      s2 = mfma16(*(const bf16x8*)&smK[krow * 64 + (((4 + lg) ^ sw) * 8)], qf1, s2);
      krow = 3 * 16 + l15; sw = krow & 7;
      s3 = mfma16(*(const bf16x8*)&smK[krow * 64 + ((lg ^ sw) * 8)], qf0, (f32x4)0.f);
      s3 = mfma16(*(const bf16x8*)&smK[krow * 64 + (((4 + lg) ^ sw) * 8)], qf1, s3);
    }

    // ---- masked online softmax over 16 values per lane ----
    float sv[16];
    float mx = -3e38f;
#pragma unroll
    for (int g = 0; g < 4; g++) {
      f32x4 sg = (g == 0) ? s0 : (g == 1) ? s1 : (g == 2) ? s2 : s3;
#pragma unroll
      for (int r = 0; r < 4; r++) {
        int k = kb + g * 16 + lg * 4 + r;
        float val = (k <= q && k > q - WIN) ? sg[r] * SC : -3e38f;
        sv[g * 4 + r] = val;
        mx = fmaxf(mx, val);
      }
    }
    mx = fmaxf(mx, __shfl_xor(mx, 16));
    mx = fmaxf(mx, __shfl_xor(mx, 32));
    float m_new = fmaxf(m_run, mx);
    float fac = __builtin_exp2f(m_run - m_new);
    float psum = 0.f;
#pragma unroll
    for (int g = 0; g < 4; g++) {
      float p0 = __builtin_exp2f(sv[g * 4 + 0] - m_new);
      float p1 = __builtin_exp2f(sv[g * 4 + 1] - m_new);
      float p2 = __builtin_exp2f(sv[g * 4 + 2] - m_new);
      float p3 = __builtin_exp2f(sv[g * 4 + 3] - m_new);
      psum += p0 + p1 + p2 + p3;
      us4 w;
      w.x = f2bf(p0); w.y = f2bf(p1); w.z = f2bf(p2); w.w = f2bf(p3);
      *(us4*)&pl[l15 * 72 + g * 16 + lg * 4] = w;   // P[q=l15][k-chunk]
    }
    psum += __shfl_xor(psum, 16);
    psum += __shfl_xor(psum, 32);
    l_run = l_run * fac + psum;
    m_run = m_new;

    // rescale O rows (row index = lg*4+r maps to query lane lg*4+r)
    float f0 = __shfl(fac, lg * 4 + 0);
    float f1 = __shfl(fac, lg * 4 + 1);
    float f2 = __shfl(fac, lg * 4 + 2);
    float f3 = __shfl(fac, lg * 4 + 3);
    o0[0] *= f0; o0[1] *= f1; o0[2] *= f2; o0[3] *= f3;
    o1[0] *= f0; o1[1] *= f1; o1[2] *= f2; o1[3] *= f3;
    o2[0] *= f0; o2[1] *= f1; o2[2] *= f2; o2[3] *= f3;
    o3[0] *= f0; o3[1] *= f1; o3[2] *= f2; o3[3] *= f3;

    asm volatile("s_waitcnt lgkmcnt(0)" ::: "memory");
    __builtin_amdgcn_sched_barrier(0);
    bf16x8 pf0 = *(const bf16x8*)&pl[l15 * 72 + lg * 8];        // P[q][k 0..31]
    bf16x8 pf1 = *(const bf16x8*)&pl[l15 * 72 + 32 + lg * 8];   // P[q][k 32..63]

    // ---- PV: O[q][d] += P * V ----
    {
      int vrow, sw;
      vrow = 0 * 16 + l15; sw = vrow & 7;
      o0 = mfma16(pf0, *(const bf16x8*)&smV[vrow * 64 + ((lg ^ sw) * 8)], o0);
      o0 = mfma16(pf1, *(const bf16x8*)&smV[vrow * 64 + (((4 + lg) ^ sw) * 8)], o0);
      vrow = 1 * 16 + l15; sw = vrow & 7;
      o1 = mfma16(pf0, *(const bf16x8*)&smV[vrow * 64 + ((lg ^ sw) * 8)], o1);
      o1 = mfma16(pf1, *(const bf16x8*)&smV[vrow * 64 + (((4 + lg) ^ sw) * 8)], o1);
      vrow = 2 * 16 + l15; sw = vrow & 7;
      o2 = mfma16(pf0, *(const bf16x8*)&smV[vrow * 64 + ((lg ^ sw) * 8)], o2);
      o2 = mfma16(pf1, *(const bf16x8*)&smV[vrow * 64 + (((4 + lg) ^ sw) * 8)], o2);
      vrow = 3 * 16 + l15; sw = vrow & 7;
      o3 = mfma16(pf0, *(const bf16x8*)&smV[vrow * 64 + ((lg ^ sw) * 8)], o3);
      o3 = mfma16(pf1, *(const bf16x8*)&smV[vrow * 64 + (((4 + lg) ^ sw) * 8)], o3);
    }
    __syncthreads();  // all waves done reading before next stage overwrites
  }

  float inv = 1.f / l_run;
  float i0 = __shfl(inv, lg * 4 + 0);
  float i1 = __shfl(inv, lg * 4 + 1);
  float i2 = __shfl(inv, lg * 4 + 2);
  float i3 = __shfl(inv, lg * 4 + 3);
  ushort_t* yb = ybuf + (size_t)qbw * CDIM + h * HD;
#pragma unroll
  for (int r = 0; r < 4; r++) {
    float ir = (r == 0) ? i0 : (r == 1) ? i1 : (r == 2) ? i2 : i3;
    size_t t = lg * 4 + r;
    yb[t * CDIM + 0  + l15] = f2bf(o0[r] * ir);
    yb[t * CDIM + 16 + l15] = f2bf(o1[r] * ir);
    yb[t * CDIM + 32 + l15] = f2bf(o2[r] * ir);
    yb[t * CDIM + 48 + l15] = f2bf(o3[r] * ir);
  }
}

// ---------------- launch ----------------
extern "C" void kernel_launch(void* const* d_in, const int* in_sizes, int n_in,
                              void* d_out, int out_size, void* d_ws, size_t ws_size,
                              hipStream_t stream) {
  const float* x  = (const float*)d_in[0];
  const float* wq = (const float*)d_in[1];
  const float* wk = (const float*)d_in[2];
  const float* wv = (const float*)d_in[3];
  const float* wo = (const float*)d_in[4];
  float* out = (float*)d_out;

  char* ws = (char*)d_ws;
  ushort_t* xb    = (ushort_t*)(ws + 0);          // 8,388,608
  ushort_t* wqkvb = (ushort_t*)(ws + 8388608);    // 3,145,728
  ushort_t* wob   = (ushort_t*)(ws + 11534336);   // 2,097,152
  ushort_t* qbuf  = (ushort_t*)(ws + 13631488);   // 8,388,608
  ushort_t* kbuf  = (ushort_t*)(ws + 22020096);   // 2,097,152
  ushort_t* vt    = (ushort_t*)(ws + 24117248);   // 2,097,152
  ushort_t* ybuf  = (ushort_t*)(ws + 26214400);   // 8,388,608
  float*    ct    = (float*)(ws + 34603008);      // 524,288
  float*    st    = (float*)(ws + 35127296);      // 524,288

  prep_kernel<<<6656, 256, 0, stream>>>(x, wq, wk, wv, wo, xb, wqkvb, wob);
  rope_kernel<<<512, 256, 0, stream>>>(ct, st);

  dim3 g1(32, 12);  // M/128 x QKVN/128
  gemm_kernel<0><<<g1, 256, 0, stream>>>(xb, wqkvb, CDIM, nullptr, qbuf, kbuf, vt, ct, st);

  attn_kernel<<<1024, 256, 0, stream>>>(qbuf, kbuf, vt, ybuf);

  dim3 g2(32, 8);   // M/128 x CDIM/128
  gemm_kernel<1><<<g2, 256, 0, stream>>>(ybuf, wob, CDIM, out, nullptr, nullptr, nullptr, nullptr, nullptr);
}

// Round 3
// 100.714 us; speedup vs baseline: 1.3399x; 1.0043x over previous
//
#include <hip/hip_runtime.h>
#include <hip/hip_bf16.h>
#include <stdint.h>

#define T_SEQ 4096
#define CDIM  1024
#define NH    16
#define NKV   4
#define HD    64
#define WIN   512
#define KVD   256      // NKV*HD
#define QKVN  1536     // CDIM + 2*KVD

typedef unsigned short ushort_t;
typedef __attribute__((ext_vector_type(8))) __bf16 bf16x8;
typedef __attribute__((ext_vector_type(4))) float  f32x4;
typedef __attribute__((ext_vector_type(4))) unsigned short us4;

__device__ inline unsigned short f2bf(float f) {
  unsigned u = __builtin_bit_cast(unsigned, f);
  u += 0x7fffu + ((u >> 16) & 1u);
  return (unsigned short)(u >> 16);
}

__device__ inline f32x4 mfma16(bf16x8 a, bf16x8 b, f32x4 c) {
  return __builtin_amdgcn_mfma_f32_16x16x32_bf16(a, b, c, 0, 0, 0);
}

__device__ inline void load_lds16(const void* g, void* s) {
  __builtin_amdgcn_global_load_lds(
      (const __attribute__((address_space(1))) void*)g,
      (__attribute__((address_space(3))) void*)s, 16, 0, 0);
}

// ---------------- prep: f32 -> bf16 conversions + rope tables ----------------
__global__ __launch_bounds__(256) void prep_kernel(
    const float* __restrict__ x,  const float* __restrict__ wq,
    const float* __restrict__ wk, const float* __restrict__ wv,
    const float* __restrict__ wo,
    ushort_t* __restrict__ xb, ushort_t* __restrict__ wqkvb,
    ushort_t* __restrict__ wob,
    float* __restrict__ ct, float* __restrict__ st) {
  const int NX  = T_SEQ * CDIM / 4;   // 1048576 vec4s
  const int NWQ = CDIM * CDIM / 4;    // 262144
  const int NWK = KVD * CDIM / 4;     // 65536
  const int NCONV = NX + 2 * NWQ + 2 * NWK;  // 6656 blocks worth
  int i = blockIdx.x * 256 + threadIdx.x;
  if (i >= NCONV) {
    // rope table region: 512 blocks
    int j = i - NCONV;
    if (j >= T_SEQ * 32) return;
    int t = j >> 5, f = j & 31;
    float inv = __builtin_exp2f(-(float)f * (13.287712379549449f / 32.0f));
    float a = (float)t * inv;
    ct[j] = cosf(a);
    st[j] = sinf(a);
    return;
  }
  const float4* src; ushort_t* dst; int off;
  if (i < NX)                        { src = (const float4*)x;  dst = xb;                              off = i; }
  else if (i < NX + NWQ)             { src = (const float4*)wq; dst = wqkvb;                           off = i - NX; }
  else if (i < NX + NWQ + NWK)       { src = (const float4*)wk; dst = wqkvb + CDIM * CDIM;             off = i - NX - NWQ; }
  else if (i < NX + NWQ + 2 * NWK)   { src = (const float4*)wv; dst = wqkvb + CDIM * CDIM + KVD * CDIM; off = i - NX - NWQ - NWK; }
  else                               { src = (const float4*)wo; dst = wob;                             off = i - NX - NWQ - 2 * NWK; }
  float4 v = src[off];
  us4 o; o.x = f2bf(v.x); o.y = f2bf(v.y); o.z = f2bf(v.z); o.w = f2bf(v.w);
  *(us4*)(dst + (size_t)off * 4) = o;
}

// ---------------- GEMM: C = A(MxK) * B(NxK)^T, bf16 in, f32 acc ----------------
template <int EPI>
__global__ __launch_bounds__(256) void gemm_kernel(
    const ushort_t* __restrict__ A, const ushort_t* __restrict__ B, int K,
    float* __restrict__ outF,
    ushort_t* __restrict__ qbuf, ushort_t* __restrict__ kbuf, ushort_t* __restrict__ vt,
    const float* __restrict__ ct, const float* __restrict__ st) {
  __shared__ __align__(16) ushort_t smA[128 * 32];
  __shared__ __align__(16) ushort_t smB[128 * 32];
  const int tid = threadIdx.x, lane = tid & 63, wid = tid >> 6;
  const int bm = blockIdx.x * 128, bn = blockIdx.y * 128;
  const int wr = wid >> 1, wc = wid & 1;
  const int l15 = lane & 15, lg = lane >> 4;
  const int srow = lane >> 2;        // 0..15
  const int scol = (lane & 3) * 8;   // 0,8,16,24

  f32x4 acc[4][4];
#pragma unroll
  for (int i = 0; i < 4; i++)
#pragma unroll
    for (int j = 0; j < 4; j++) acc[i][j] = (f32x4)0.0f;

  for (int kt = 0; kt < K; kt += 32) {
#pragma unroll
    for (int i = 0; i < 2; i++) {
      int ch = i * 4 + wid;  // 0..7, per-wave uniform
      load_lds16(A + (size_t)(bm + ch * 16 + srow) * K + kt + scol, (char*)smA + ch * 1024);
      load_lds16(B + (size_t)(bn + ch * 16 + srow) * K + kt + scol, (char*)smB + ch * 1024);
    }
    __syncthreads();
    bf16x8 af[4], bfr[4];
#pragma unroll
    for (int mi = 0; mi < 4; mi++) af[mi] = *(const bf16x8*)&smA[(wr * 64 + mi * 16 + l15) * 32 + lg * 8];
#pragma unroll
    for (int ni = 0; ni < 4; ni++) bfr[ni] = *(const bf16x8*)&smB[(wc * 64 + ni * 16 + l15) * 32 + lg * 8];
#pragma unroll
    for (int mi = 0; mi < 4; mi++)
#pragma unroll
      for (int ni = 0; ni < 4; ni++) acc[mi][ni] = mfma16(af[mi], bfr[ni], acc[mi][ni]);
    __syncthreads();
  }

  const int col0 = bn + wc * 64;  // wave's 64-col span, multiple of 64
  if (EPI == 1) {
#pragma unroll
    for (int mi = 0; mi < 4; mi++) {
      int r0 = bm + wr * 64 + mi * 16 + lg * 4;
#pragma unroll
      for (int ni = 0; ni < 4; ni++) {
        int c = col0 + ni * 16 + l15;
#pragma unroll
        for (int r = 0; r < 4; r++) outF[(size_t)(r0 + r) * CDIM + c] = acc[mi][ni][r];
      }
    }
  } else {
    if (col0 < CDIM + KVD) {
      // Q or K: apply rope. pairs (d, d+32) are frags ni and ni+2, same lane.
      bool isQ = (col0 < CDIM);
      ushort_t* obuf = isQ ? qbuf : kbuf;
      int ostride = isQ ? CDIM : KVD;
      int obase = isQ ? col0 : col0 - CDIM;
#pragma unroll
      for (int mi = 0; mi < 4; mi++) {
        int r0 = bm + wr * 64 + mi * 16 + lg * 4;
#pragma unroll
        for (int ni = 0; ni < 2; ni++) {
          int dd = ni * 16 + l15;  // 0..31 within head
#pragma unroll
          for (int r = 0; r < 4; r++) {
            int t = r0 + r;
            float c_ = ct[t * 32 + dd], s_ = st[t * 32 + dd];
            float lo = acc[mi][ni][r], hi = acc[mi][ni + 2][r];
            obuf[(size_t)t * ostride + obase + dd]      = f2bf(lo * c_ - hi * s_);
            obuf[(size_t)t * ostride + obase + dd + 32] = f2bf(hi * c_ + lo * s_);
          }
        }
      }
    } else {
      // V: transpose to vt[cv][T], cv = kvh*64+d. 4 consecutive rows -> 8B store.
#pragma unroll
      for (int mi = 0; mi < 4; mi++) {
        int t0 = bm + wr * 64 + mi * 16 + lg * 4;
#pragma unroll
        for (int ni = 0; ni < 4; ni++) {
          int cv = col0 + ni * 16 + l15 - (CDIM + KVD);  // 0..255
          us4 o;
          o.x = f2bf(acc[mi][ni][0]); o.y = f2bf(acc[mi][ni][1]);
          o.z = f2bf(acc[mi][ni][2]); o.w = f2bf(acc[mi][ni][3]);
          *(us4*)&vt[(size_t)cv * T_SEQ + t0] = o;
        }
      }
    }
  }
}

// ---------------- flash attention, sliding window ----------------
// Block = 64 queries of one head, 4 waves x 16 queries. KBLK = 64.
// 2-phase pipeline: double-buffered K/V LDS tiles, next tile's global_load_lds
// issued before computing current tile; raw s_barrier + counted vmcnt(4).
__global__ __launch_bounds__(256) void attn_kernel(
    const ushort_t* __restrict__ qbuf, const ushort_t* __restrict__ kbuf,
    const ushort_t* __restrict__ vt, ushort_t* __restrict__ ybuf) {
  __shared__ __align__(16) ushort_t smK[2][64 * 64];
  __shared__ __align__(16) ushort_t smV[2][64 * 64];
  __shared__ __align__(16) ushort_t plds[4][16 * 64];  // stride 64, XOR chunk swizzle
  const int tid = threadIdx.x, lane = tid & 63, wid = tid >> 6;
  const int l15 = lane & 15, lg = lane >> 4;
  const int blk = blockIdx.x;
  const int h = blk >> 6;            // 64 q-tiles per head
  const int qb = (blk & 63) * 64;    // block query base
  const int kvh = h >> 2;            // n_rep = 4
  const int qbw = qb + wid * 16;     // wave query base

  // staging lane decomposition: inst covers 8 rows of 128B; lane -> (row, chunk)
  const int r8 = lane >> 3;          // 0..7 row within inst
  const int cc = lane & 7;           // dest 16B chunk within row
  const int sc = ((cc ^ r8) * 8);    // swizzled source elem offset within row
  const int ra = wid * 8 + r8;
  const int rb = (wid + 4) * 8 + r8;

  int kb0 = qb - (WIN - 1);
  if (kb0 < 0) kb0 = 0;
  kb0 &= ~63;
  const int nt = ((qb + 63) - kb0) / 64 + 1;

#define STAGE(buf, kbase)                                                                  \
  do {                                                                                     \
    load_lds16(kbuf + (size_t)((kbase) + ra) * KVD + kvh * HD + sc, (char*)smK[buf] + wid * 1024);        \
    load_lds16(kbuf + (size_t)((kbase) + rb) * KVD + kvh * HD + sc, (char*)smK[buf] + (wid + 4) * 1024);  \
    load_lds16(vt + (size_t)(kvh * HD + ra) * T_SEQ + (kbase) + sc, (char*)smV[buf] + wid * 1024);        \
    load_lds16(vt + (size_t)(kvh * HD + rb) * T_SEQ + (kbase) + sc, (char*)smV[buf] + (wid + 4) * 1024);  \
  } while (0)

  STAGE(0, kb0);

  // Q fragments (issued after stage; both in flight)
  const ushort_t* qrow = qbuf + (size_t)(qbw + l15) * CDIM + h * HD;
  bf16x8 qf0 = *(const bf16x8*)(qrow + lg * 8);
  bf16x8 qf1 = *(const bf16x8*)(qrow + 32 + lg * 8);

  f32x4 o0 = (f32x4)0.f, o1 = (f32x4)0.f, o2 = (f32x4)0.f, o3 = (f32x4)0.f;
  float m_run = -1e30f, l_run = 0.f;
  const float SC = 0.125f * 1.4426950408889634f;  // scale * log2(e)
  const int q = qbw + l15;
  ushort_t* pl = &plds[wid][0];
  const int pswz = (l15 & 7) << 4;   // byte XOR for plds chunk swizzle

  int cur = 0;
  for (int t = 0; t < nt; ++t) {
    const int kb = kb0 + t * 64;
    if (t + 1 < nt) {
      STAGE(cur ^ 1, kb + 64);
      asm volatile("s_waitcnt vmcnt(4)" ::: "memory");
    } else {
      asm volatile("s_waitcnt vmcnt(0)" ::: "memory");
    }
    __builtin_amdgcn_sched_barrier(0);
    __builtin_amdgcn_s_barrier();
    __builtin_amdgcn_sched_barrier(0);

    if (kb <= qbw + 15) {  // wave-uniform: skip tiles fully above diagonal
      const ushort_t* sk = smK[cur];
      const ushort_t* sv_ = smV[cur];
      // ---- QK^T: S^T[k][q], 4 key groups of 16 ----
      f32x4 s0, s1, s2, s3;
      __builtin_amdgcn_s_setprio(1);
      {
        int krow, sw;
        krow = 0 * 16 + l15; sw = krow & 7;
        s0 = mfma16(*(const bf16x8*)&sk[krow * 64 + ((lg ^ sw) * 8)], qf0, (f32x4)0.f);
        s0 = mfma16(*(const bf16x8*)&sk[krow * 64 + (((4 + lg) ^ sw) * 8)], qf1, s0);
        krow = 1 * 16 + l15; sw = krow & 7;
        s1 = mfma16(*(const bf16x8*)&sk[krow * 64 + ((lg ^ sw) * 8)], qf0, (f32x4)0.f);
        s1 = mfma16(*(const bf16x8*)&sk[krow * 64 + (((4 + lg) ^ sw) * 8)], qf1, s1);
        krow = 2 * 16 + l15; sw = krow & 7;
        s2 = mfma16(*(const bf16x8*)&sk[krow * 64 + ((lg ^ sw) * 8)], qf0, (f32x4)0.f);
        s2 = mfma16(*(const bf16x8*)&sk[krow * 64 + (((4 + lg) ^ sw) * 8)], qf1, s2);
        krow = 3 * 16 + l15; sw = krow & 7;
        s3 = mfma16(*(const bf16x8*)&sk[krow * 64 + ((lg ^ sw) * 8)], qf0, (f32x4)0.f);
        s3 = mfma16(*(const bf16x8*)&sk[krow * 64 + (((4 + lg) ^ sw) * 8)], qf1, s3);
      }
      __builtin_amdgcn_s_setprio(0);

      // ---- masked online softmax over 16 values per lane ----
      float sv[16];
      float mx = -3e38f;
      const bool nomask = (kb + 63 <= qbw) && (kb > qbw + 15 - WIN);
      if (nomask) {
#pragma unroll
        for (int g = 0; g < 4; g++) {
          f32x4 sg = (g == 0) ? s0 : (g == 1) ? s1 : (g == 2) ? s2 : s3;
#pragma unroll
          for (int r = 0; r < 4; r++) {
            float val = sg[r] * SC;
            sv[g * 4 + r] = val;
            mx = fmaxf(mx, val);
          }
        }
      } else {
#pragma unroll
        for (int g = 0; g < 4; g++) {
          f32x4 sg = (g == 0) ? s0 : (g == 1) ? s1 : (g == 2) ? s2 : s3;
#pragma unroll
          for (int r = 0; r < 4; r++) {
            int k = kb + g * 16 + lg * 4 + r;
            float val = (k <= q && k > q - WIN) ? sg[r] * SC : -3e38f;
            sv[g * 4 + r] = val;
            mx = fmaxf(mx, val);
          }
        }
      }
      mx = fmaxf(mx, __shfl_xor(mx, 16));
      mx = fmaxf(mx, __shfl_xor(mx, 32));

      // defer-max: only rescale when the row max actually grew (> +8 in log2)
      float fac = 1.f;
      if (!__all(mx <= m_run + 8.f)) {
        float m_new = fmaxf(m_run, mx);
        fac = __builtin_exp2f(m_run - m_new);
        m_run = m_new;
        float f0 = __shfl(fac, lg * 4 + 0);
        float f1 = __shfl(fac, lg * 4 + 1);
        float f2 = __shfl(fac, lg * 4 + 2);
        float f3 = __shfl(fac, lg * 4 + 3);
        o0[0] *= f0; o0[1] *= f1; o0[2] *= f2; o0[3] *= f3;
        o1[0] *= f0; o1[1] *= f1; o1[2] *= f2; o1[3] *= f3;
        o2[0] *= f0; o2[1] *= f1; o2[2] *= f2; o2[3] *= f3;
        o3[0] *= f0; o3[1] *= f1; o3[2] *= f2; o3[3] *= f3;
      }

      float psum = 0.f;
#pragma unroll
      for (int g = 0; g < 4; g++) {
        float p0 = __builtin_exp2f(sv[g * 4 + 0] - m_run);
        float p1 = __builtin_exp2f(sv[g * 4 + 1] - m_run);
        float p2 = __builtin_exp2f(sv[g * 4 + 2] - m_run);
        float p3 = __builtin_exp2f(sv[g * 4 + 3] - m_run);
        psum += p0 + p1 + p2 + p3;
        us4 w;
        w.x = f2bf(p0); w.y = f2bf(p1); w.z = f2bf(p2); w.w = f2bf(p3);
        int offg = g * 32 + lg * 8;  // byte offset of this us4 in the 128B row
        *(us4*)((char*)pl + l15 * 128 + (offg ^ pswz)) = w;
      }
      psum += __shfl_xor(psum, 16);
      psum += __shfl_xor(psum, 32);
      l_run = l_run * fac + psum;

      asm volatile("s_waitcnt lgkmcnt(0)" ::: "memory");
      __builtin_amdgcn_sched_barrier(0);
      bf16x8 pf0 = *(const bf16x8*)((const char*)pl + l15 * 128 + ((lg * 16) ^ pswz));
      bf16x8 pf1 = *(const bf16x8*)((const char*)pl + l15 * 128 + ((64 + lg * 16) ^ pswz));

      // ---- PV: O[q][d] += P * V ----
      __builtin_amdgcn_s_setprio(1);
      {
        int vrow, sw;
        vrow = 0 * 16 + l15; sw = vrow & 7;
        o0 = mfma16(pf0, *(const bf16x8*)&sv_[vrow * 64 + ((lg ^ sw) * 8)], o0);
        o0 = mfma16(pf1, *(const bf16x8*)&sv_[vrow * 64 + (((4 + lg) ^ sw) * 8)], o0);
        vrow = 1 * 16 + l15; sw = vrow & 7;
        o1 = mfma16(pf0, *(const bf16x8*)&sv_[vrow * 64 + ((lg ^ sw) * 8)], o1);
        o1 = mfma16(pf1, *(const bf16x8*)&sv_[vrow * 64 + (((4 + lg) ^ sw) * 8)], o1);
        vrow = 2 * 16 + l15; sw = vrow & 7;
        o2 = mfma16(pf0, *(const bf16x8*)&sv_[vrow * 64 + ((lg ^ sw) * 8)], o2);
        o2 = mfma16(pf1, *(const bf16x8*)&sv_[vrow * 64 + (((4 + lg) ^ sw) * 8)], o2);
        vrow = 3 * 16 + l15; sw = vrow & 7;
        o3 = mfma16(pf0, *(const bf16x8*)&sv_[vrow * 64 + ((lg ^ sw) * 8)], o3);
        o3 = mfma16(pf1, *(const bf16x8*)&sv_[vrow * 64 + (((4 + lg) ^ sw) * 8)], o3);
      }
      __builtin_amdgcn_s_setprio(0);
    }
    __builtin_amdgcn_sched_barrier(0);
    __builtin_amdgcn_s_barrier();  // all waves done reading buf[cur] before overwrite
    __builtin_amdgcn_sched_barrier(0);
    cur ^= 1;
  }
#undef STAGE

  float inv = 1.f / l_run;
  float i0 = __shfl(inv, lg * 4 + 0);
  float i1 = __shfl(inv, lg * 4 + 1);
  float i2 = __shfl(inv, lg * 4 + 2);
  float i3 = __shfl(inv, lg * 4 + 3);
  ushort_t* yb = ybuf + (size_t)qbw * CDIM + h * HD;
#pragma unroll
  for (int r = 0; r < 4; r++) {
    float ir = (r == 0) ? i0 : (r == 1) ? i1 : (r == 2) ? i2 : i3;
    size_t t = lg * 4 + r;
    yb[t * CDIM + 0  + l15] = f2bf(o0[r] * ir);
    yb[t * CDIM + 16 + l15] = f2bf(o1[r] * ir);
    yb[t * CDIM + 32 + l15] = f2bf(o2[r] * ir);
    yb[t * CDIM + 48 + l15] = f2bf(o3[r] * ir);
  }
}

// ---------------- launch ----------------
extern "C" void kernel_launch(void* const* d_in, const int* in_sizes, int n_in,
                              void* d_out, int out_size, void* d_ws, size_t ws_size,
                              hipStream_t stream) {
  const float* x  = (const float*)d_in[0];
  const float* wq = (const float*)d_in[1];
  const float* wk = (const float*)d_in[2];
  const float* wv = (const float*)d_in[3];
  const float* wo = (const float*)d_in[4];
  float* out = (float*)d_out;

  char* ws = (char*)d_ws;
  ushort_t* xb    = (ushort_t*)(ws + 0);          // 8,388,608
  ushort_t* wqkvb = (ushort_t*)(ws + 8388608);    // 3,145,728
  ushort_t* wob   = (ushort_t*)(ws + 11534336);   // 2,097,152
  ushort_t* qbuf  = (ushort_t*)(ws + 13631488);   // 8,388,608
  ushort_t* kbuf  = (ushort_t*)(ws + 22020096);   // 2,097,152
  ushort_t* vt    = (ushort_t*)(ws + 24117248);   // 2,097,152
  ushort_t* ybuf  = (ushort_t*)(ws + 26214400);   // 8,388,608
  float*    ct    = (float*)(ws + 34603008);      // 524,288
  float*    st    = (float*)(ws + 35127296);      // 524,288

  prep_kernel<<<7168, 256, 0, stream>>>(x, wq, wk, wv, wo, xb, wqkvb, wob, ct, st);

  dim3 g1(32, 12);  // M/128 x QKVN/128
  gemm_kernel<0><<<g1, 256, 0, stream>>>(xb, wqkvb, CDIM, nullptr, qbuf, kbuf, vt, ct, st);

  attn_kernel<<<1024, 256, 0, stream>>>(qbuf, kbuf, vt, ybuf);

  dim3 g2(32, 8);   // M/128 x CDIM/128
  gemm_kernel<1><<<g2, 256, 0, stream>>>(ybuf, wob, CDIM, out, nullptr, nullptr, nullptr, nullptr, nullptr);
}

// Round 4
// 92.218 us; speedup vs baseline: 1.4633x; 1.0921x over previous
//
#include <hip/hip_runtime.h>
#include <hip/hip_bf16.h>
#include <stdint.h>

#define T_SEQ 4096
#define CDIM  1024
#define NH    16
#define NKV   4
#define HD    64
#define WIN   512
#define KVD   256      // NKV*HD
#define QKVN  1536     // CDIM + 2*KVD

typedef unsigned short ushort_t;
typedef __attribute__((ext_vector_type(8))) __bf16 bf16x8;
typedef __attribute__((ext_vector_type(4))) float  f32x4;
typedef __attribute__((ext_vector_type(4))) unsigned short us4;

__device__ inline unsigned short f2bf(float f) {
  unsigned u = __builtin_bit_cast(unsigned, f);
  u += 0x7fffu + ((u >> 16) & 1u);
  return (unsigned short)(u >> 16);
}

__device__ inline f32x4 mfma16(bf16x8 a, bf16x8 b, f32x4 c) {
  return __builtin_amdgcn_mfma_f32_16x16x32_bf16(a, b, c, 0, 0, 0);
}

__device__ inline void load_lds16(const void* g, void* s) {
  __builtin_amdgcn_global_load_lds(
      (const __attribute__((address_space(1))) void*)g,
      (__attribute__((address_space(3))) void*)s, 16, 0, 0);
}

// ---------------- prep: f32 -> bf16 conversions + rope tables ----------------
__global__ __launch_bounds__(256) void prep_kernel(
    const float* __restrict__ x,  const float* __restrict__ wq,
    const float* __restrict__ wk, const float* __restrict__ wv,
    const float* __restrict__ wo,
    ushort_t* __restrict__ xb, ushort_t* __restrict__ wqkvb,
    ushort_t* __restrict__ wob,
    float* __restrict__ ct, float* __restrict__ st) {
  const int NX  = T_SEQ * CDIM / 4;   // 1048576 vec4s
  const int NWQ = CDIM * CDIM / 4;    // 262144
  const int NWK = KVD * CDIM / 4;     // 65536
  const int NCONV = NX + 2 * NWQ + 2 * NWK;
  int i = blockIdx.x * 256 + threadIdx.x;
  if (i >= NCONV) {
    int j = i - NCONV;
    if (j >= T_SEQ * 32) return;
    int t = j >> 5, f = j & 31;
    float inv = __builtin_exp2f(-(float)f * (13.287712379549449f / 32.0f));
    float a = (float)t * inv;
    ct[j] = cosf(a);
    st[j] = sinf(a);
    return;
  }
  const float4* src; ushort_t* dst; int off;
  if (i < NX)                        { src = (const float4*)x;  dst = xb;                              off = i; }
  else if (i < NX + NWQ)             { src = (const float4*)wq; dst = wqkvb;                           off = i - NX; }
  else if (i < NX + NWQ + NWK)       { src = (const float4*)wk; dst = wqkvb + CDIM * CDIM;             off = i - NX - NWQ; }
  else if (i < NX + NWQ + 2 * NWK)   { src = (const float4*)wv; dst = wqkvb + CDIM * CDIM + KVD * CDIM; off = i - NX - NWQ - NWK; }
  else                               { src = (const float4*)wo; dst = wob;                             off = i - NX - NWQ - 2 * NWK; }
  float4 v = src[off];
  us4 o; o.x = f2bf(v.x); o.y = f2bf(v.y); o.z = f2bf(v.z); o.w = f2bf(v.w);
  *(us4*)(dst + (size_t)off * 4) = o;
}

// ---------------- GEMM: C = A(MxK) * B(NxK)^T, bf16 in, f32 acc ----------------
// BM=64, BN=128. 4 waves 2x2, wave-tile 32x64, acc[2][4].
template <int EPI>
__global__ __launch_bounds__(256) void gemm_kernel(
    const ushort_t* __restrict__ A, const ushort_t* __restrict__ B, int K,
    float* __restrict__ outF,
    ushort_t* __restrict__ qbuf, ushort_t* __restrict__ kbuf, ushort_t* __restrict__ vt,
    const float* __restrict__ ct, const float* __restrict__ st) {
  __shared__ __align__(16) ushort_t smA[64 * 32];
  __shared__ __align__(16) ushort_t smB[128 * 32];
  const int tid = threadIdx.x, lane = tid & 63, wid = tid >> 6;
  const int bm = blockIdx.x * 64, bn = blockIdx.y * 128;
  const int wr = wid >> 1, wc = wid & 1;
  const int l15 = lane & 15, lg = lane >> 4;
  const int srow = lane >> 2;        // 0..15
  const int scol = (lane & 3) * 8;   // 0,8,16,24

  f32x4 acc[2][4];
#pragma unroll
  for (int i = 0; i < 2; i++)
#pragma unroll
    for (int j = 0; j < 4; j++) acc[i][j] = (f32x4)0.0f;

  for (int kt = 0; kt < K; kt += 32) {
    // A: 4 insts (one per wave); B: 8 insts (two per wave)
    load_lds16(A + (size_t)(bm + wid * 16 + srow) * K + kt + scol, (char*)smA + wid * 1024);
    load_lds16(B + (size_t)(bn + wid * 16 + srow) * K + kt + scol, (char*)smB + wid * 1024);
    load_lds16(B + (size_t)(bn + (wid + 4) * 16 + srow) * K + kt + scol, (char*)smB + (wid + 4) * 1024);
    __syncthreads();
    bf16x8 af[2], bfr[4];
#pragma unroll
    for (int mi = 0; mi < 2; mi++) af[mi] = *(const bf16x8*)&smA[(wr * 32 + mi * 16 + l15) * 32 + lg * 8];
#pragma unroll
    for (int ni = 0; ni < 4; ni++) bfr[ni] = *(const bf16x8*)&smB[(wc * 64 + ni * 16 + l15) * 32 + lg * 8];
#pragma unroll
    for (int mi = 0; mi < 2; mi++)
#pragma unroll
      for (int ni = 0; ni < 4; ni++) acc[mi][ni] = mfma16(af[mi], bfr[ni], acc[mi][ni]);
    __syncthreads();
  }

  const int col0 = bn + wc * 64;  // wave's 64-col span
  if (EPI == 1) {
#pragma unroll
    for (int mi = 0; mi < 2; mi++) {
      int r0 = bm + wr * 32 + mi * 16 + lg * 4;
#pragma unroll
      for (int ni = 0; ni < 4; ni++) {
        int c = col0 + ni * 16 + l15;
#pragma unroll
        for (int r = 0; r < 4; r++) outF[(size_t)(r0 + r) * CDIM + c] = acc[mi][ni][r];
      }
    }
  } else {
    if (col0 < CDIM + KVD) {
      bool isQ = (col0 < CDIM);
      ushort_t* obuf = isQ ? qbuf : kbuf;
      int ostride = isQ ? CDIM : KVD;
      int obase = isQ ? col0 : col0 - CDIM;
#pragma unroll
      for (int mi = 0; mi < 2; mi++) {
        int r0 = bm + wr * 32 + mi * 16 + lg * 4;
#pragma unroll
        for (int ni = 0; ni < 2; ni++) {
          int dd = ni * 16 + l15;  // 0..31 within head
#pragma unroll
          for (int r = 0; r < 4; r++) {
            int t = r0 + r;
            float c_ = ct[t * 32 + dd], s_ = st[t * 32 + dd];
            float lo = acc[mi][ni][r], hi = acc[mi][ni + 2][r];
            obuf[(size_t)t * ostride + obase + dd]      = f2bf(lo * c_ - hi * s_);
            obuf[(size_t)t * ostride + obase + dd + 32] = f2bf(hi * c_ + lo * s_);
          }
        }
      }
    } else {
#pragma unroll
      for (int mi = 0; mi < 2; mi++) {
        int t0 = bm + wr * 32 + mi * 16 + lg * 4;
#pragma unroll
        for (int ni = 0; ni < 4; ni++) {
          int cv = col0 + ni * 16 + l15 - (CDIM + KVD);  // 0..255
          us4 o;
          o.x = f2bf(acc[mi][ni][0]); o.y = f2bf(acc[mi][ni][1]);
          o.z = f2bf(acc[mi][ni][2]); o.w = f2bf(acc[mi][ni][3]);
          *(us4*)&vt[(size_t)cv * T_SEQ + t0] = o;
        }
      }
    }
  }
}

// ---------------- flash attention, sliding window ----------------
// Block = 128 queries of one head, 4 waves x 32 queries (2 halves of 16).
// K/V fragments register-cached, reused across both query halves.
__global__ __launch_bounds__(256) void attn_kernel(
    const ushort_t* __restrict__ qbuf, const ushort_t* __restrict__ kbuf,
    const ushort_t* __restrict__ vt, ushort_t* __restrict__ ybuf) {
  __shared__ __align__(16) ushort_t smK[2][64 * 64];
  __shared__ __align__(16) ushort_t smV[2][64 * 64];
  __shared__ __align__(16) ushort_t plds[4][32 * 64];  // 4KB per wave
  const int tid = threadIdx.x, lane = tid & 63, wid = tid >> 6;
  const int l15 = lane & 15, lg = lane >> 4;
  const int blk = blockIdx.x;
  const int h = blk >> 5;            // 32 q-blocks per head
  const int qb = (blk & 31) * 128;   // block query base
  const int kvh = h >> 2;            // n_rep = 4
  const int qbw = qb + wid * 32;     // wave query base (32 queries)

  const int r8 = lane >> 3;          // 0..7 row within staging inst
  const int cc = lane & 7;           // dest 16B chunk within row
  const int sc = ((cc ^ r8) * 8);    // swizzled source elem offset
  const int ra = wid * 8 + r8;
  const int rb = (wid + 4) * 8 + r8;

  int kb0 = qb - (WIN - 1);
  if (kb0 < 0) kb0 = 0;
  kb0 &= ~63;
  const int nt = ((qb + 127) - kb0) / 64 + 1;

#define STAGE(buf, kbase)                                                                  \
  do {                                                                                     \
    load_lds16(kbuf + (size_t)((kbase) + ra) * KVD + kvh * HD + sc, (char*)smK[buf] + wid * 1024);        \
    load_lds16(kbuf + (size_t)((kbase) + rb) * KVD + kvh * HD + sc, (char*)smK[buf] + (wid + 4) * 1024);  \
    load_lds16(vt + (size_t)(kvh * HD + ra) * T_SEQ + (kbase) + sc, (char*)smV[buf] + wid * 1024);        \
    load_lds16(vt + (size_t)(kvh * HD + rb) * T_SEQ + (kbase) + sc, (char*)smV[buf] + (wid + 4) * 1024);  \
  } while (0)

  STAGE(0, kb0);

  // Q fragments: [half][d-half]
  bf16x8 qf[2][2];
#pragma unroll
  for (int h2 = 0; h2 < 2; h2++) {
    const ushort_t* qrow = qbuf + (size_t)(qbw + h2 * 16 + l15) * CDIM + h * HD;
    qf[h2][0] = *(const bf16x8*)(qrow + lg * 8);
    qf[h2][1] = *(const bf16x8*)(qrow + 32 + lg * 8);
  }

  f32x4 o[2][4];
#pragma unroll
  for (int i = 0; i < 2; i++)
#pragma unroll
    for (int j = 0; j < 4; j++) o[i][j] = (f32x4)0.f;
  float m_run[2] = {-1e30f, -1e30f};
  float l_run[2] = {0.f, 0.f};
  const float SC = 0.125f * 1.4426950408889634f;  // scale * log2(e)
  ushort_t* pl = &plds[wid][0];
  const int sw = l15 & 7;
  const int pswz = sw << 4;

  int cur = 0;
  for (int t = 0; t < nt; ++t) {
    const int kb = kb0 + t * 64;
    if (t + 1 < nt) {
      STAGE(cur ^ 1, kb + 64);
      asm volatile("s_waitcnt vmcnt(4)" ::: "memory");
    } else {
      asm volatile("s_waitcnt vmcnt(0)" ::: "memory");
    }
    __builtin_amdgcn_sched_barrier(0);
    __builtin_amdgcn_s_barrier();
    __builtin_amdgcn_sched_barrier(0);

    if (kb <= qbw + 31) {  // wave-uniform skip of tiles above diagonal
      const ushort_t* sk = smK[cur];
      const ushort_t* sv_ = smV[cur];

      // K fragments cached: [k-group][d-half]
      bf16x8 kf[4][2];
#pragma unroll
      for (int g = 0; g < 4; g++) {
        kf[g][0] = *(const bf16x8*)&sk[(g * 16 + l15) * 64 + ((lg ^ sw) * 8)];
        kf[g][1] = *(const bf16x8*)&sk[(g * 16 + l15) * 64 + (((4 + lg) ^ sw) * 8)];
      }

      // ---- QK^T for both halves: S^T[k][q] ----
      f32x4 s[2][4];
      __builtin_amdgcn_s_setprio(1);
#pragma unroll
      for (int h2 = 0; h2 < 2; h2++)
#pragma unroll
        for (int g = 0; g < 4; g++) {
          s[h2][g] = mfma16(kf[g][0], qf[h2][0], (f32x4)0.f);
          s[h2][g] = mfma16(kf[g][1], qf[h2][1], s[h2][g]);
        }
      __builtin_amdgcn_s_setprio(0);

      const bool nomask = (kb + 63 <= qbw) && (kb > qbw + 31 - WIN);
#pragma unroll
      for (int h2 = 0; h2 < 2; h2++) {
        const int q = qbw + h2 * 16 + l15;
        float sv[16];
        float mx = -3e38f;
        if (nomask) {
#pragma unroll
          for (int g = 0; g < 4; g++)
#pragma unroll
            for (int r = 0; r < 4; r++) {
              float val = s[h2][g][r] * SC;
              sv[g * 4 + r] = val;
              mx = fmaxf(mx, val);
            }
        } else {
#pragma unroll
          for (int g = 0; g < 4; g++)
#pragma unroll
            for (int r = 0; r < 4; r++) {
              int k = kb + g * 16 + lg * 4 + r;
              float val = (k <= q && k > q - WIN) ? s[h2][g][r] * SC : -3e38f;
              sv[g * 4 + r] = val;
              mx = fmaxf(mx, val);
            }
        }
        mx = fmaxf(mx, __shfl_xor(mx, 16));
        mx = fmaxf(mx, __shfl_xor(mx, 32));

        float fac = 1.f;
        if (!__all(mx <= m_run[h2] + 8.f)) {
          float m_new = fmaxf(m_run[h2], mx);
          fac = __builtin_exp2f(m_run[h2] - m_new);
          m_run[h2] = m_new;
          float f0 = __shfl(fac, lg * 4 + 0);
          float f1 = __shfl(fac, lg * 4 + 1);
          float f2 = __shfl(fac, lg * 4 + 2);
          float f3 = __shfl(fac, lg * 4 + 3);
#pragma unroll
          for (int n = 0; n < 4; n++) {
            o[h2][n][0] *= f0; o[h2][n][1] *= f1;
            o[h2][n][2] *= f2; o[h2][n][3] *= f3;
          }
        }

        float psum = 0.f;
#pragma unroll
        for (int g = 0; g < 4; g++) {
          float p0 = __builtin_exp2f(sv[g * 4 + 0] - m_run[h2]);
          float p1 = __builtin_exp2f(sv[g * 4 + 1] - m_run[h2]);
          float p2 = __builtin_exp2f(sv[g * 4 + 2] - m_run[h2]);
          float p3 = __builtin_exp2f(sv[g * 4 + 3] - m_run[h2]);
          psum += p0 + p1 + p2 + p3;
          us4 w;
          w.x = f2bf(p0); w.y = f2bf(p1); w.z = f2bf(p2); w.w = f2bf(p3);
          *(us4*)((char*)pl + (h2 * 16 + l15) * 128 + ((g * 32 + lg * 8) ^ pswz)) = w;
        }
        psum += __shfl_xor(psum, 16);
        psum += __shfl_xor(psum, 32);
        l_run[h2] = l_run[h2] * fac + psum;
      }

      asm volatile("s_waitcnt lgkmcnt(0)" ::: "memory");
      __builtin_amdgcn_sched_barrier(0);
      bf16x8 pf[2][2];
#pragma unroll
      for (int h2 = 0; h2 < 2; h2++) {
        pf[h2][0] = *(const bf16x8*)((const char*)pl + (h2 * 16 + l15) * 128 + ((lg * 16) ^ pswz));
        pf[h2][1] = *(const bf16x8*)((const char*)pl + (h2 * 16 + l15) * 128 + ((64 + lg * 16) ^ pswz));
      }

      // ---- PV: V fragments read once, used by both halves ----
      __builtin_amdgcn_s_setprio(1);
#pragma unroll
      for (int n = 0; n < 4; n++) {
        bf16x8 v0 = *(const bf16x8*)&sv_[(n * 16 + l15) * 64 + ((lg ^ sw) * 8)];
        bf16x8 v1 = *(const bf16x8*)&sv_[(n * 16 + l15) * 64 + (((4 + lg) ^ sw) * 8)];
        o[0][n] = mfma16(pf[0][0], v0, o[0][n]);
        o[0][n] = mfma16(pf[0][1], v1, o[0][n]);
        o[1][n] = mfma16(pf[1][0], v0, o[1][n]);
        o[1][n] = mfma16(pf[1][1], v1, o[1][n]);
      }
      __builtin_amdgcn_s_setprio(0);
    }
    __builtin_amdgcn_sched_barrier(0);
    __builtin_amdgcn_s_barrier();  // all waves done reading buf[cur]
    __builtin_amdgcn_sched_barrier(0);
    cur ^= 1;
  }
#undef STAGE

#pragma unroll
  for (int h2 = 0; h2 < 2; h2++) {
    float inv = 1.f / l_run[h2];
    float i0 = __shfl(inv, lg * 4 + 0);
    float i1 = __shfl(inv, lg * 4 + 1);
    float i2 = __shfl(inv, lg * 4 + 2);
    float i3 = __shfl(inv, lg * 4 + 3);
    ushort_t* yb = ybuf + (size_t)(qbw + h2 * 16) * CDIM + h * HD;
#pragma unroll
    for (int r = 0; r < 4; r++) {
      float ir = (r == 0) ? i0 : (r == 1) ? i1 : (r == 2) ? i2 : i3;
      size_t t = lg * 4 + r;
      yb[t * CDIM + 0  + l15] = f2bf(o[h2][0][r] * ir);
      yb[t * CDIM + 16 + l15] = f2bf(o[h2][1][r] * ir);
      yb[t * CDIM + 32 + l15] = f2bf(o[h2][2][r] * ir);
      yb[t * CDIM + 48 + l15] = f2bf(o[h2][3][r] * ir);
    }
  }
}

// ---------------- launch ----------------
extern "C" void kernel_launch(void* const* d_in, const int* in_sizes, int n_in,
                              void* d_out, int out_size, void* d_ws, size_t ws_size,
                              hipStream_t stream) {
  const float* x  = (const float*)d_in[0];
  const float* wq = (const float*)d_in[1];
  const float* wk = (const float*)d_in[2];
  const float* wv = (const float*)d_in[3];
  const float* wo = (const float*)d_in[4];
  float* out = (float*)d_out;

  char* ws = (char*)d_ws;
  ushort_t* xb    = (ushort_t*)(ws + 0);          // 8,388,608
  ushort_t* wqkvb = (ushort_t*)(ws + 8388608);    // 3,145,728
  ushort_t* wob   = (ushort_t*)(ws + 11534336);   // 2,097,152
  ushort_t* qbuf  = (ushort_t*)(ws + 13631488);   // 8,388,608
  ushort_t* kbuf  = (ushort_t*)(ws + 22020096);   // 2,097,152
  ushort_t* vt    = (ushort_t*)(ws + 24117248);   // 2,097,152
  ushort_t* ybuf  = (ushort_t*)(ws + 26214400);   // 8,388,608
  float*    ct    = (float*)(ws + 34603008);      // 524,288
  float*    st    = (float*)(ws + 35127296);      // 524,288

  prep_kernel<<<7168, 256, 0, stream>>>(x, wq, wk, wv, wo, xb, wqkvb, wob, ct, st);

  dim3 g1(64, 12);  // M/64 x QKVN/128
  gemm_kernel<0><<<g1, 256, 0, stream>>>(xb, wqkvb, CDIM, nullptr, qbuf, kbuf, vt, ct, st);

  attn_kernel<<<512, 256, 0, stream>>>(qbuf, kbuf, vt, ybuf);

  dim3 g2(64, 8);   // M/64 x CDIM/128
  gemm_kernel<1><<<g2, 256, 0, stream>>>(ybuf, wob, CDIM, out, nullptr, nullptr, nullptr, nullptr, nullptr);
}